// Round 1
// baseline (5271.897 us; speedup 1.0000x reference)
//
#include <hip/hip_runtime.h>
#include <hip/hip_bf16.h>

#define TSTEPS 256
#define NG 4
#define GDIM 2048

typedef short bf16x8 __attribute__((ext_vector_type(8)));
typedef float f32x4 __attribute__((ext_vector_type(4)));

__device__ __forceinline__ unsigned short f2bf(float f) {
    union { float f; unsigned u; } v; v.f = f;
    unsigned r = v.u + 0x7FFFu + ((v.u >> 16) & 1u);
    return (unsigned short)(r >> 16);
}
__device__ __forceinline__ float bf2f(unsigned short s) {
    union { unsigned u; float f; } v; v.u = ((unsigned)s) << 16; return v.f;
}

__global__ void hq_marker(float* out) { out[0] = 12345.0f; }

// W2 [4][1024 k][1024 h] f32  ->  W2T [4][1024 h][1024 k] bf16
__global__ void hq_transpose(const float* __restrict__ in, unsigned short* __restrict__ out) {
    __shared__ float tile[64][65];
    const int R = 1024, C = 1024;
    int r0 = blockIdx.y * 64, c0 = blockIdx.x * 64;
    const float* src = in + (long)blockIdx.z * R * C;
    unsigned short* dst = out + (long)blockIdx.z * R * C;
    int col = threadIdx.x & 63, rr = threadIdx.x >> 6;
#pragma unroll
    for (int i = 0; i < 16; ++i) {
        int row = rr + i * 4;
        tile[row][col] = src[(long)(r0 + row) * C + c0 + col];
    }
    __syncthreads();
#pragma unroll
    for (int i = 0; i < 16; ++i) {
        int row = rr + i * 4;
        dst[(long)(c0 + row) * R + r0 + col] = f2bf(tile[col][row]);
    }
}

// beff[g][h] = sum_k b1[g][k]*W2[g][k][h] + b2[g][h]   (uses W2T bf16)
__global__ void hq_beff(const unsigned short* __restrict__ w2t, const float* __restrict__ b1,
                        const float* __restrict__ b2, float* __restrict__ beff) {
    int g = blockIdx.y;
    int h = blockIdx.x * 256 + threadIdx.x;
    const unsigned short* row = w2t + ((long)(g * 1024 + h)) * 1024;
    float s = 0.f;
    for (int k = 0; k < 1024; k += 8) {
        bf16x8 v = *reinterpret_cast<const bf16x8*>(row + k);
#pragma unroll
        for (int j = 0; j < 8; ++j) s += bf2f((unsigned short)v[j]) * b1[g * 1024 + k + j];
    }
    beff[g * 1024 + h] = s + b2[g * 1024 + h];
}

// WeffT[g][h][d] = sum_k W2T[g][h][k] * W1[g][d][k]   (C' = [h rows] x [d cols])
__global__ void hq_weff(const unsigned short* __restrict__ w2t, const float* __restrict__ w1,
                        unsigned short* __restrict__ wefft) {
    __shared__ unsigned short atile[64][136];
    const int g = blockIdx.z;
    const int d0 = blockIdx.x * 64;
    const int h0 = blockIdx.y * 64;
    const int tid = threadIdx.x;
    const int w = tid >> 6, lane = tid & 63;
    const int fr = lane & 15, fq = lane >> 4;
    f32x4 acc[4] = {};
    const int drow = d0 + w * 16 + fr;
    const float* bsrc = w1 + ((long)g * GDIM + drow) * 1024;
    for (int kc = 0; kc < 8; ++kc) {
#pragma unroll
        for (int i = 0; i < 4; ++i) {
            int id = tid + i * 256;
            int row = id >> 4, c8 = id & 15;
            bf16x8 v = *reinterpret_cast<const bf16x8*>(
                w2t + ((long)(g * 1024 + h0 + row)) * 1024 + kc * 128 + c8 * 8);
            *reinterpret_cast<bf16x8*>(&atile[row][c8 * 8]) = v;
        }
        __syncthreads();
#pragma unroll
        for (int kk = 0; kk < 4; ++kk) {
            int kl = kk * 32 + fq * 8;
            int kg = kc * 128 + kl;
            float4 bA = *reinterpret_cast<const float4*>(bsrc + kg);
            float4 bB = *reinterpret_cast<const float4*>(bsrc + kg + 4);
            bf16x8 bfv;
            bfv[0] = (short)f2bf(bA.x); bfv[1] = (short)f2bf(bA.y);
            bfv[2] = (short)f2bf(bA.z); bfv[3] = (short)f2bf(bA.w);
            bfv[4] = (short)f2bf(bB.x); bfv[5] = (short)f2bf(bB.y);
            bfv[6] = (short)f2bf(bB.z); bfv[7] = (short)f2bf(bB.w);
#pragma unroll
            for (int mi = 0; mi < 4; ++mi) {
                bf16x8 af = *reinterpret_cast<const bf16x8*>(&atile[mi * 16 + fr][kl]);
                acc[mi] = __builtin_amdgcn_mfma_f32_16x16x32_bf16(af, bfv, acc[mi], 0, 0, 0);
            }
        }
        __syncthreads();
    }
#pragma unroll
    for (int mi = 0; mi < 4; ++mi)
#pragma unroll
        for (int r = 0; r < 4; ++r) {
            int h = h0 + mi * 16 + fq * 4 + r;
            int d = d0 + w * 16 + fr;
            wefft[((long)(g * 1024 + h)) * GDIM + d] = f2bf(acc[mi][r]);
        }
}

// inputs f32 -> bf16 (16,777,216 elems)
__global__ void hq_xconv(const float* __restrict__ x, unsigned short* __restrict__ xbf) {
    long i = (long)blockIdx.x * 256 + threadIdx.x;
    for (; i < 4194304L; i += 524288L) {
        float4 v = reinterpret_cast<const float4*>(x)[i];
        ushort4 o;
        o.x = f2bf(v.x); o.y = f2bf(v.y); o.z = f2bf(v.z); o.w = f2bf(v.w);
        reinterpret_cast<ushort4*>(xbf)[i] = o;
    }
}

// One timestep: z = [x_t | hx] * WeffT^T (+beff) ; gates ; cx/hx update.
// grid 128 = (bgt 2) x (ht 64); block 1024 thr = 16 waves = (bg 2) x (kq 8)
__global__ __launch_bounds__(1024, 1) void hq_step(
    const unsigned short* __restrict__ xbf,
    const unsigned short* __restrict__ hxin,
    const unsigned short* __restrict__ wefft,
    const float* __restrict__ beff,
    float* __restrict__ cx,
    float* __restrict__ outs,
    float* __restrict__ hxf_out,
    float* __restrict__ cxf_out,
    unsigned short* __restrict__ hxout,
    int tstep)
{
    __shared__ float zpart[NG][8][32][16];   // 64 KB
    const int tid = threadIdx.x;
    const int wave = tid >> 6, lane = tid & 63;
    const int fr = lane & 15, fq = lane >> 4;
    const int bg = wave & 1, kq = wave >> 1;
    const int bgt = blockIdx.x >> 6, ht = blockIdx.x & 63;
    const int arow = bgt * 32 + bg * 16 + fr;
    const int kbase = kq * 256 + fq * 8;
    const unsigned short* aptr;
    if (kq < 4) aptr = xbf + ((long)tstep * 64 + arow) * 1024 + kbase;
    else        aptr = hxin + (long)arow * 1024 + (kbase - 1024);
    const unsigned short* bptr = wefft + ((long)(ht * 16 + fr)) * GDIM + kbase;
    f32x4 acc[NG] = {};
#pragma unroll
    for (int it = 0; it < 8; ++it) {
        bf16x8 af = *reinterpret_cast<const bf16x8*>(aptr + it * 32);
#pragma unroll
        for (int g = 0; g < NG; ++g) {
            bf16x8 bfv = *reinterpret_cast<const bf16x8*>(bptr + (long)g * 2097152 + it * 32);
            acc[g] = __builtin_amdgcn_mfma_f32_16x16x32_bf16(af, bfv, acc[g], 0, 0, 0);
        }
    }
#pragma unroll
    for (int g = 0; g < NG; ++g)
#pragma unroll
        for (int r = 0; r < 4; ++r)
            zpart[g][kq][bg * 16 + fq * 4 + r][fr] = acc[g][r];
    __syncthreads();
    if (tid < 512) {
        const int brow = tid >> 4, hl = tid & 15;
        const int b = bgt * 32 + brow;
        const int h = ht * 16 + hl;
        float z[NG];
#pragma unroll
        for (int g = 0; g < NG; ++g) {
            float s = beff[g * 1024 + h];
#pragma unroll
            for (int q = 0; q < 8; ++q) s += zpart[g][q][brow][hl];
            z[g] = s;
        }
        float fgate = 1.f / (1.f + __expf(-z[0]));
        float igate = 1.f / (1.f + __expf(-z[1]));
        float ggate = 2.f / (1.f + __expf(-2.f * z[2])) - 1.f;
        float ogate = 1.f / (1.f + __expf(-z[3]));
        const int idx = b * 1024 + h;
        float c = fgate * cx[idx] + igate * ggate;
        float hv = ogate * (2.f / (1.f + __expf(-2.f * c)) - 1.f);
        cx[idx] = c;
        outs[((long)tstep * 64 + b) * 1024 + h] = hv;
        hxout[idx] = f2bf(hv);
        if (tstep == TSTEPS - 1) { hxf_out[idx] = hv; cxf_out[idx] = c; }
    }
}

extern "C" void kernel_launch(void* const* d_in, const int* in_sizes, int n_in,
                              void* d_out, int out_size, void* d_ws, size_t ws_size,
                              hipStream_t stream) {
    (void)in_sizes; (void)n_in; (void)out_size;
    const float* x  = (const float*)d_in[0];
    const float* W1 = (const float*)d_in[1];
    const float* b1 = (const float*)d_in[2];
    const float* W2 = (const float*)d_in[3];
    const float* b2 = (const float*)d_in[4];
    float* outs = (float*)d_out;
    float* hxf = outs + 16777216L;
    float* cxf = hxf + 65536;

    // ws layout (bytes)
    const size_t off_wefft = 0;          // 16,777,216  (WeffT bf16 [4][1024][2048])
    const size_t off_xbf   = 16777216;   // 33,554,432  (xbf bf16; W2T bf16 aliased at its head)
    const size_t off_w2t   = off_xbf;    //  8,388,608  (consumed before xconv overwrites)
    const size_t off_hx0   = 50331648;   //    131,072
    const size_t off_cx    = 50462720;   //    262,144
    const size_t off_hx1   = 50724864;   //    131,072
    const size_t off_beff  = 50855936;   //     16,384
    const size_t need      = 50872320;
    if (ws_size < need) { hq_marker<<<1, 1, 0, stream>>>((float*)d_out); return; }

    char* ws = (char*)d_ws;
    unsigned short* wefft = (unsigned short*)(ws + off_wefft);
    unsigned short* xbf   = (unsigned short*)(ws + off_xbf);
    unsigned short* w2t   = (unsigned short*)(ws + off_w2t);
    unsigned short* hx0   = (unsigned short*)(ws + off_hx0);
    unsigned short* hx1   = (unsigned short*)(ws + off_hx1);
    float* cx   = (float*)(ws + off_cx);
    float* beff = (float*)(ws + off_beff);

    hipMemsetAsync(ws + off_hx0, 0, 131072 + 262144, stream);   // hx0 + cx = 0
    hq_transpose<<<dim3(16, 16, 4), 256, 0, stream>>>(W2, w2t);
    hq_beff<<<dim3(4, 4), 256, 0, stream>>>(w2t, b1, b2, beff);
    hq_weff<<<dim3(32, 16, 4), 256, 0, stream>>>(w2t, W1, wefft);
    hq_xconv<<<2048, 256, 0, stream>>>(x, xbf);
    for (int t = 0; t < TSTEPS; ++t) {
        const unsigned short* hin = (t & 1) ? hx1 : hx0;
        unsigned short* hout      = (t & 1) ? hx0 : hx1;
        hq_step<<<128, 1024, 0, stream>>>(xbf, hin, wefft, beff, cx, outs, hxf, cxf, hout, t);
    }
}

// Round 2
// 3855.399 us; speedup vs baseline: 1.3674x; 1.3674x over previous
//
#include <hip/hip_runtime.h>
#include <hip/hip_bf16.h>

#define TSTEPS 256
#define NBLK 256

typedef short bf16x8 __attribute__((ext_vector_type(8)));
typedef float f32x4 __attribute__((ext_vector_type(4)));

__device__ __forceinline__ unsigned short f2bf(float f) {
    union { float f; unsigned u; } v; v.f = f;
    unsigned r = v.u + 0x7FFFu + ((v.u >> 16) & 1u);
    return (unsigned short)(r >> 16);
}
__device__ __forceinline__ float bf2f(unsigned short s) {
    union { unsigned u; float f; } v; v.u = ((unsigned)s) << 16; return v.f;
}

__global__ void hq_marker(float* out) { out[0] = 12345.0f; }

// W2 [4][1024 k][1024 h] f32  ->  W2T [4][1024 h][1024 k] bf16
__global__ void hq_transpose(const float* __restrict__ in, unsigned short* __restrict__ out) {
    __shared__ float tile[64][65];
    const int R = 1024, C = 1024;
    int r0 = blockIdx.y * 64, c0 = blockIdx.x * 64;
    const float* src = in + (long)blockIdx.z * R * C;
    unsigned short* dst = out + (long)blockIdx.z * R * C;
    int col = threadIdx.x & 63, rr = threadIdx.x >> 6;
#pragma unroll
    for (int i = 0; i < 16; ++i) {
        int row = rr + i * 4;
        tile[row][col] = src[(long)(r0 + row) * C + c0 + col];
    }
    __syncthreads();
#pragma unroll
    for (int i = 0; i < 16; ++i) {
        int row = rr + i * 4;
        dst[(long)(c0 + row) * R + r0 + col] = f2bf(tile[col][row]);
    }
}

// beff[g][h] = sum_k b1[g][k]*W2[g][k][h] + b2[g][h]
__global__ void hq_beff(const unsigned short* __restrict__ w2t, const float* __restrict__ b1,
                        const float* __restrict__ b2, float* __restrict__ beff) {
    int g = blockIdx.y;
    int h = blockIdx.x * 256 + threadIdx.x;
    const unsigned short* row = w2t + ((long)(g * 1024 + h)) * 1024;
    float s = 0.f;
    for (int k = 0; k < 1024; k += 8) {
        bf16x8 v = *reinterpret_cast<const bf16x8*>(row + k);
#pragma unroll
        for (int j = 0; j < 8; ++j) s += bf2f((unsigned short)v[j]) * b1[g * 1024 + k + j];
    }
    beff[g * 1024 + h] = s + b2[g * 1024 + h];
}

// WeffT[g][h][d] = sum_k W2T[g][h][k] * W1[g][d][k]
__global__ void hq_weff(const unsigned short* __restrict__ w2t, const float* __restrict__ w1,
                        unsigned short* __restrict__ wefft) {
    __shared__ unsigned short atile[64][136];
    const int g = blockIdx.z;
    const int d0 = blockIdx.x * 64;
    const int h0 = blockIdx.y * 64;
    const int tid = threadIdx.x;
    const int w = tid >> 6, lane = tid & 63;
    const int fr = lane & 15, fq = lane >> 4;
    f32x4 acc[4] = {};
    const int drow = d0 + w * 16 + fr;
    const float* bsrc = w1 + ((long)g * 2048 + drow) * 1024;
    for (int kc = 0; kc < 8; ++kc) {
#pragma unroll
        for (int i = 0; i < 4; ++i) {
            int id = tid + i * 256;
            int row = id >> 4, c8 = id & 15;
            bf16x8 v = *reinterpret_cast<const bf16x8*>(
                w2t + ((long)(g * 1024 + h0 + row)) * 1024 + kc * 128 + c8 * 8);
            *reinterpret_cast<bf16x8*>(&atile[row][c8 * 8]) = v;
        }
        __syncthreads();
#pragma unroll
        for (int kk = 0; kk < 4; ++kk) {
            int kl = kk * 32 + fq * 8;
            int kg = kc * 128 + kl;
            float4 bA = *reinterpret_cast<const float4*>(bsrc + kg);
            float4 bB = *reinterpret_cast<const float4*>(bsrc + kg + 4);
            bf16x8 bfv;
            bfv[0] = (short)f2bf(bA.x); bfv[1] = (short)f2bf(bA.y);
            bfv[2] = (short)f2bf(bA.z); bfv[3] = (short)f2bf(bA.w);
            bfv[4] = (short)f2bf(bB.x); bfv[5] = (short)f2bf(bB.y);
            bfv[6] = (short)f2bf(bB.z); bfv[7] = (short)f2bf(bB.w);
#pragma unroll
            for (int mi = 0; mi < 4; ++mi) {
                bf16x8 af = *reinterpret_cast<const bf16x8*>(&atile[mi * 16 + fr][kl]);
                acc[mi] = __builtin_amdgcn_mfma_f32_16x16x32_bf16(af, bfv, acc[mi], 0, 0, 0);
            }
        }
        __syncthreads();
    }
#pragma unroll
    for (int mi = 0; mi < 4; ++mi)
#pragma unroll
        for (int r = 0; r < 4; ++r) {
            int h = h0 + mi * 16 + fq * 4 + r;
            int d = d0 + w * 16 + fr;
            wefft[((long)(g * 1024 + h)) * 2048 + d] = f2bf(acc[r == r ? mi : mi][r]);
        }
}

// inputs f32 -> bf16
__global__ void hq_xconv(const float* __restrict__ x, unsigned short* __restrict__ xbf) {
    long i = (long)blockIdx.x * 256 + threadIdx.x;
    for (; i < 4194304L; i += 524288L) {
        float4 v = reinterpret_cast<const float4*>(x)[i];
        ushort4 o;
        o.x = f2bf(v.x); o.y = f2bf(v.y); o.z = f2bf(v.z); o.w = f2bf(v.w);
        reinterpret_cast<ushort4*>(xbf)[i] = o;
    }
}

// Persistent sequential kernel.
// grid 256 = (bq 2) x (cb 128). Block: rows b0..b0+31, cols = 8 h x 4 gates (32 MFMA cols).
// block 1024 thr = 16 waves = (mt 2) x (kq 8). Weights register-resident (64 VGPR/wave).
__global__ __launch_bounds__(1024, 4) void hq_seq(
    const unsigned short* __restrict__ xbf,     // [256][64][1024] bf16
    const unsigned short* __restrict__ wefft,   // [4][1024][2048] bf16
    const float* __restrict__ beff,             // [4][1024]
    float* __restrict__ outs,                   // [256][64][1024] f32
    float* __restrict__ hxf, float* __restrict__ cxf,
    unsigned short* __restrict__ hxbuf,         // [2][64][1024] bf16 (buf0 zeroed)
    unsigned* __restrict__ ctrl)                // [0]=count (monotonic), [1]=gen
{
    __shared__ float zpart[8][2][32][17];       // [kq][mt][col][row] ~34.8 KB
    const int tid = threadIdx.x;
    const int lane = tid & 63, wave = tid >> 6;
    const int fr = lane & 15, fq = lane >> 4;
    const int mt = wave & 1, kq = wave >> 1;
    const int bq = blockIdx.x >> 7, cb = blockIdx.x & 127;
    const int b0 = bq * 32, ho = cb * 8;
    const int k0 = kq * 256;

    // ---- preload B fragments (weights) into registers: 2 nt x 8 ksteps ----
    bf16x8 breg[2][8];
#pragma unroll
    for (int nt = 0; nt < 2; ++nt) {
        const int col = nt * 16 + fr;
        const int g = col >> 3, hl = col & 7;
        const unsigned short* wrow =
            wefft + ((long)(g * 1024 + ho + hl)) * 2048 + k0 + fq * 8;
#pragma unroll
        for (int s = 0; s < 8; ++s) breg[nt][s] = *(const bf16x8*)(wrow + s * 32);
    }

    // ---- epilogue-persistent state (threads 0..255): cx in registers ----
    const int eb = tid >> 3, ehl = tid & 7;
    float creg = 0.f;
    float be[4] = {0.f, 0.f, 0.f, 0.f};
    if (tid < 256) {
#pragma unroll
        for (int g = 0; g < 4; ++g) be[g] = beff[g * 1024 + ho + ehl];
    }

    const int arow = b0 + mt * 16 + fr;

    for (int t = 0; t < TSTEPS; ++t) {
        const unsigned short* hx_r = hxbuf + (t & 1) * 65536;
        unsigned short* hx_w = hxbuf + ((t & 1) ^ 1) * 65536;
        const unsigned short* aptr = (kq < 4)
            ? xbf + ((long)(t * 64 + arow)) * 1024 + k0 + fq * 8
            : hx_r + (long)arow * 1024 + (k0 - 1024) + fq * 8;

        f32x4 acc0 = {0.f, 0.f, 0.f, 0.f};
        f32x4 acc1 = {0.f, 0.f, 0.f, 0.f};
#pragma unroll
        for (int s = 0; s < 8; ++s) {
            bf16x8 af = *(const bf16x8*)(aptr + s * 32);
            acc0 = __builtin_amdgcn_mfma_f32_16x16x32_bf16(af, breg[0][s], acc0, 0, 0, 0);
            acc1 = __builtin_amdgcn_mfma_f32_16x16x32_bf16(af, breg[1][s], acc1, 0, 0, 0);
        }
#pragma unroll
        for (int r = 0; r < 4; ++r) {
            zpart[kq][mt][fr][fq * 4 + r]      = acc0[r];
            zpart[kq][mt][16 + fr][fq * 4 + r] = acc1[r];
        }
        __syncthreads();

        if (tid < 256) {
            const int emt = eb >> 4, erow = eb & 15;
            float z0 = be[0], z1 = be[1], z2 = be[2], z3 = be[3];
#pragma unroll
            for (int q = 0; q < 8; ++q) {
                z0 += zpart[q][emt][ehl][erow];
                z1 += zpart[q][emt][8 + ehl][erow];
                z2 += zpart[q][emt][16 + ehl][erow];
                z3 += zpart[q][emt][24 + ehl][erow];
            }
            float fg = 1.f / (1.f + __expf(-z0));
            float ig = 1.f / (1.f + __expf(-z1));
            float gg = 2.f / (1.f + __expf(-2.f * z2)) - 1.f;
            float og = 1.f / (1.f + __expf(-z3));
            creg = fg * creg + ig * gg;
            float hv = og * (2.f / (1.f + __expf(-2.f * creg)) - 1.f);
            const int b = b0 + eb, h = ho + ehl;
            outs[((long)(t * 64 + b)) * 1024 + h] = hv;
            hx_w[b * 1024 + h] = f2bf(hv);
            if (t == TSTEPS - 1) { hxf[b * 1024 + h] = hv; cxf[b * 1024 + h] = creg; }
        }
        __syncthreads();

        // ---- grid barrier (monotonic counter, agent-scope) ----
        if (tid == 0) {
            __builtin_amdgcn_fence(__ATOMIC_RELEASE, "agent");   // drain + wbl2
            unsigned a = __hip_atomic_fetch_add(&ctrl[0], 1u, __ATOMIC_RELAXED,
                                                __HIP_MEMORY_SCOPE_AGENT);
            const unsigned tgt = (unsigned)(t + 1) * NBLK;
            if (a == tgt - 1u) {
                __hip_atomic_store(&ctrl[1], (unsigned)(t + 1), __ATOMIC_RELAXED,
                                   __HIP_MEMORY_SCOPE_AGENT);
            } else {
                int guard = 0;
                while (__hip_atomic_load(&ctrl[1], __ATOMIC_RELAXED,
                                         __HIP_MEMORY_SCOPE_AGENT) < (unsigned)(t + 1)) {
                    __builtin_amdgcn_s_sleep(1);
                    if (++guard > 40000) break;   // graceful bail, never hang
                }
            }
            __builtin_amdgcn_fence(__ATOMIC_ACQUIRE, "agent");   // inv L1/L2
        }
        __syncthreads();
    }
}

extern "C" void kernel_launch(void* const* d_in, const int* in_sizes, int n_in,
                              void* d_out, int out_size, void* d_ws, size_t ws_size,
                              hipStream_t stream) {
    (void)in_sizes; (void)n_in; (void)out_size;
    const float* x  = (const float*)d_in[0];
    const float* W1 = (const float*)d_in[1];
    const float* b1 = (const float*)d_in[2];
    const float* W2 = (const float*)d_in[3];
    const float* b2 = (const float*)d_in[4];
    float* outs = (float*)d_out;
    float* hxf = outs + 16777216L;
    float* cxf = hxf + 65536;

    // ws layout (bytes)
    const size_t off_wefft = 0;          // 16,777,216  WeffT bf16 [4][1024][2048]
    const size_t off_xbf   = 16777216;   // 33,554,432  xbf bf16 (w2t aliased at head)
    const size_t off_w2t   = off_xbf;    //  8,388,608  consumed before xconv overwrites
    const size_t off_hx    = 50331648;   //    262,144  hx ping-pong [2][64][1024] bf16
    const size_t off_beff  = 50593792;   //     16,384
    const size_t off_ctrl  = 50610176;   //        256
    const size_t need      = 50610432;
    if (ws_size < need) { hq_marker<<<1, 1, 0, stream>>>((float*)d_out); return; }

    char* ws = (char*)d_ws;
    unsigned short* wefft = (unsigned short*)(ws + off_wefft);
    unsigned short* xbf   = (unsigned short*)(ws + off_xbf);
    unsigned short* w2t   = (unsigned short*)(ws + off_w2t);
    unsigned short* hxbuf = (unsigned short*)(ws + off_hx);
    float* beff = (float*)(ws + off_beff);
    unsigned* ctrl = (unsigned*)(ws + off_ctrl);

    hipMemsetAsync(ws + off_hx, 0, 262144, stream);   // hx buffers = 0
    hipMemsetAsync(ws + off_ctrl, 0, 256, stream);    // barrier state = 0
    hq_transpose<<<dim3(16, 16, 4), 256, 0, stream>>>(W2, w2t);
    hq_beff<<<dim3(4, 4), 256, 0, stream>>>(w2t, b1, b2, beff);
    hq_weff<<<dim3(32, 16, 4), 256, 0, stream>>>(w2t, W1, wefft);
    hq_xconv<<<2048, 256, 0, stream>>>(x, xbf);

    const unsigned short* xbf_c = xbf;
    const unsigned short* wefft_c = wefft;
    const float* beff_c = beff;
    void* args[] = { (void*)&xbf_c, (void*)&wefft_c, (void*)&beff_c,
                     (void*)&outs, (void*)&hxf, (void*)&cxf,
                     (void*)&hxbuf, (void*)&ctrl };
    hipError_t ce = hipLaunchCooperativeKernel((const void*)hq_seq, dim3(NBLK), dim3(1024),
                                               args, 0, stream);
    if (ce != hipSuccess) {
        // co-residency still holds (1 block/CU, 256 blocks <= 256 CUs)
        hq_seq<<<NBLK, 1024, 0, stream>>>(xbf, wefft, beff, outs, hxf, cxf, hxbuf, ctrl);
    }
}

// Round 5
// 3514.258 us; speedup vs baseline: 1.5001x; 1.0971x over previous
//
#include <hip/hip_runtime.h>
#include <hip/hip_bf16.h>

#define TSTEPS 256
#define NBLK 256

typedef short bf16x8 __attribute__((ext_vector_type(8)));
typedef float f32x4 __attribute__((ext_vector_type(4)));

__device__ __forceinline__ unsigned short f2bf(float f) {
    union { float f; unsigned u; } v; v.f = f;
    unsigned r = v.u + 0x7FFFu + ((v.u >> 16) & 1u);
    return (unsigned short)(r >> 16);
}
__device__ __forceinline__ float bf2f(unsigned short s) {
    union { unsigned u; float f; } v; v.u = ((unsigned)s) << 16; return v.f;
}

__global__ void hq_marker(float* out) { out[0] = 12345.0f; }

// W2 [4][1024 k][1024 h] f32  ->  W2T [4][1024 h][1024 k] bf16
__global__ void hq_transpose(const float* __restrict__ in, unsigned short* __restrict__ out) {
    __shared__ float tile[64][65];
    const int R = 1024, C = 1024;
    int r0 = blockIdx.y * 64, c0 = blockIdx.x * 64;
    const float* src = in + (long)blockIdx.z * R * C;
    unsigned short* dst = out + (long)blockIdx.z * R * C;
    int col = threadIdx.x & 63, rr = threadIdx.x >> 6;
#pragma unroll
    for (int i = 0; i < 16; ++i) {
        int row = rr + i * 4;
        tile[row][col] = src[(long)(r0 + row) * C + c0 + col];
    }
    __syncthreads();
#pragma unroll
    for (int i = 0; i < 16; ++i) {
        int row = rr + i * 4;
        dst[(long)(c0 + row) * R + r0 + col] = f2bf(tile[col][row]);
    }
}

// beff[g][h] = sum_k b1[g][k]*W2[g][k][h] + b2[g][h]
__global__ void hq_beff(const unsigned short* __restrict__ w2t, const float* __restrict__ b1,
                        const float* __restrict__ b2, float* __restrict__ beff) {
    int g = blockIdx.y;
    int h = blockIdx.x * 256 + threadIdx.x;
    const unsigned short* row = w2t + ((long)(g * 1024 + h)) * 1024;
    float s = 0.f;
    for (int k = 0; k < 1024; k += 8) {
        bf16x8 v = *reinterpret_cast<const bf16x8*>(row + k);
#pragma unroll
        for (int j = 0; j < 8; ++j) s += bf2f((unsigned short)v[j]) * b1[g * 1024 + k + j];
    }
    beff[g * 1024 + h] = s + b2[g * 1024 + h];
}

// WeffT[g][h][d] = sum_k W2T[g][h][k] * W1[g][d][k]
__global__ void hq_weff(const unsigned short* __restrict__ w2t, const float* __restrict__ w1,
                        unsigned short* __restrict__ wefft) {
    __shared__ unsigned short atile[64][136];
    const int g = blockIdx.z;
    const int d0 = blockIdx.x * 64;
    const int h0 = blockIdx.y * 64;
    const int tid = threadIdx.x;
    const int w = tid >> 6, lane = tid & 63;
    const int fr = lane & 15, fq = lane >> 4;
    f32x4 acc[4] = {};
    const int drow = d0 + w * 16 + fr;
    const float* bsrc = w1 + ((long)g * 2048 + drow) * 1024;
    for (int kc = 0; kc < 8; ++kc) {
#pragma unroll
        for (int i = 0; i < 4; ++i) {
            int id = tid + i * 256;
            int row = id >> 4, c8 = id & 15;
            bf16x8 v = *reinterpret_cast<const bf16x8*>(
                w2t + ((long)(g * 1024 + h0 + row)) * 1024 + kc * 128 + c8 * 8);
            *reinterpret_cast<bf16x8*>(&atile[row][c8 * 8]) = v;
        }
        __syncthreads();
#pragma unroll
        for (int kk = 0; kk < 4; ++kk) {
            int kl = kk * 32 + fq * 8;
            int kg = kc * 128 + kl;
            float4 bA = *reinterpret_cast<const float4*>(bsrc + kg);
            float4 bB = *reinterpret_cast<const float4*>(bsrc + kg + 4);
            bf16x8 bfv;
            bfv[0] = (short)f2bf(bA.x); bfv[1] = (short)f2bf(bA.y);
            bfv[2] = (short)f2bf(bA.z); bfv[3] = (short)f2bf(bA.w);
            bfv[4] = (short)f2bf(bB.x); bfv[5] = (short)f2bf(bB.y);
            bfv[6] = (short)f2bf(bB.z); bfv[7] = (short)f2bf(bB.w);
#pragma unroll
            for (int mi = 0; mi < 4; ++mi) {
                bf16x8 af = *reinterpret_cast<const bf16x8*>(&atile[mi * 16 + fr][kl]);
                acc[mi] = __builtin_amdgcn_mfma_f32_16x16x32_bf16(af, bfv, acc[mi], 0, 0, 0);
            }
        }
        __syncthreads();
    }
#pragma unroll
    for (int mi = 0; mi < 4; ++mi)
#pragma unroll
        for (int r = 0; r < 4; ++r) {
            int h = h0 + mi * 16 + fq * 4 + r;
            int d = d0 + w * 16 + fr;
            wefft[((long)(g * 1024 + h)) * 2048 + d] = f2bf(acc[mi][r]);
        }
}

// inputs f32 -> bf16
__global__ void hq_xconv(const float* __restrict__ x, unsigned short* __restrict__ xbf) {
    long i = (long)blockIdx.x * 256 + threadIdx.x;
    for (; i < 4194304L; i += 524288L) {
        float4 v = reinterpret_cast<const float4*>(x)[i];
        ushort4 o;
        o.x = f2bf(v.x); o.y = f2bf(v.y); o.z = f2bf(v.z); o.w = f2bf(v.w);
        reinterpret_cast<ushort4*>(xbf)[i] = o;
    }
}

// ---- coherence helpers: agent-scope atomics (LLC point-to-point, no fences) ----
__device__ __forceinline__ bf16x8 coh_load16B(const unsigned* p) {
    union { unsigned u[4]; bf16x8 v; } r;
#pragma unroll
    for (int j = 0; j < 4; ++j)
        r.u[j] = __hip_atomic_load(p + j, __ATOMIC_RELAXED, __HIP_MEMORY_SCOPE_AGENT);
    return r.v;
}
__device__ __forceinline__ void vm_drain() {
    asm volatile("s_waitcnt vmcnt(0)" ::: "memory");
}
__device__ __forceinline__ void wait_flags(const unsigned* flags, unsigned tgt) {
    const int lane = threadIdx.x & 63;
    const unsigned* p = flags + lane * 4;
    for (int guard = 0; guard < (1 << 16); ++guard) {
        unsigned a = __hip_atomic_load(p + 0, __ATOMIC_RELAXED, __HIP_MEMORY_SCOPE_AGENT);
        unsigned b = __hip_atomic_load(p + 1, __ATOMIC_RELAXED, __HIP_MEMORY_SCOPE_AGENT);
        unsigned c = __hip_atomic_load(p + 2, __ATOMIC_RELAXED, __HIP_MEMORY_SCOPE_AGENT);
        unsigned d = __hip_atomic_load(p + 3, __ATOMIC_RELAXED, __HIP_MEMORY_SCOPE_AGENT);
        unsigned m = a < b ? a : b;
        unsigned n = c < d ? c : d;
        m = m < n ? m : n;
        if (__all(m >= tgt)) return;
        __builtin_amdgcn_s_sleep(1);
    }
}

// Persistent sequential kernel, fence-free flag barrier.
// grid 256 = (bq 2) x (cb 128); block 1024 = 16 waves, wave kq owns 128 K-slice.
// kq 0-7: x part (never waits). kq 8-15: hx part (flag-gated). waves 0-3: epilogue.
__global__ __launch_bounds__(1024, 4) void hq_seq(
    const unsigned short* __restrict__ xbf,     // [256][64][1024] bf16
    const unsigned short* __restrict__ wefft,   // [4][1024][2048] bf16
    const float* __restrict__ beff,             // [4][1024]
    float* __restrict__ outs,                   // [256][64][1024] f32
    float* __restrict__ hxf, float* __restrict__ cxf,
    unsigned short* __restrict__ hxbuf,         // [2][64][1024] bf16 (no init needed)
    unsigned* __restrict__ flags,               // [256] zeroed per launch
    unsigned* __restrict__ spin)                // [256] zeroed per launch
{
    __shared__ float zpart[16][2][32][16];      // exactly 64 KB, row XOR-swizzled
    const int tid = threadIdx.x;
    const int lane = tid & 63, kq = tid >> 6;
    const int fr = lane & 15, fq = lane >> 4;
    const int bid = blockIdx.x;
    const int bq = bid >> 7, cb = bid & 127;
    const int b0 = bq * 32, ho = cb * 8;
    const int k0 = kq * 128;

    // ---- preload B fragments: [nt 2][ks 4] = 32 regs/lane ----
    bf16x8 breg[2][4];
#pragma unroll
    for (int nt = 0; nt < 2; ++nt) {
        const int col = nt * 16 + fr;
        const int g = col >> 3, hl = col & 7;
        const unsigned short* wrow = wefft + ((long)(g * 1024 + ho + hl)) * 2048 + k0 + fq * 8;
#pragma unroll
        for (int s = 0; s < 4; ++s) breg[nt][s] = *(const bf16x8*)(wrow + s * 32);
    }

    const int eb = tid >> 3, ehl = tid & 7;
    float creg = 0.f;
    float be[4] = {0.f, 0.f, 0.f, 0.f};
    if (tid < 256) {
#pragma unroll
        for (int g = 0; g < 4; ++g) be[g] = beff[g * 1024 + ho + ehl];
    }

    for (int t = 0; t < TSTEPS; ++t) {
        bf16x8 af[8];                            // [mt*4 + s]
        if (kq < 8) {
            const unsigned short* p0 = xbf + ((long)(t * 64 + b0 + fr)) * 1024 + k0 + fq * 8;
            const unsigned short* p1 = p0 + 16 * 1024;
#pragma unroll
            for (int s = 0; s < 4; ++s) {
                af[s]     = *(const bf16x8*)(p0 + s * 32);
                af[4 + s] = *(const bf16x8*)(p1 + s * 32);
            }
        } else if (t == 0) {
#pragma unroll
            for (int i = 0; i < 8; ++i) af[i] = (bf16x8){0, 0, 0, 0, 0, 0, 0, 0};
        } else {
            if (kq == 8) {
                wait_flags(flags, (unsigned)t);
                if (lane == 0)
                    __hip_atomic_store(spin + bid, (unsigned)t, __ATOMIC_RELAXED,
                                       __HIP_MEMORY_SCOPE_WORKGROUP);
            } else {
                while (__hip_atomic_load(spin + bid, __ATOMIC_RELAXED,
                                         __HIP_MEMORY_SCOPE_WORKGROUP) < (unsigned)t)
                    __builtin_amdgcn_s_sleep(1);
            }
            const unsigned short* hx_r = hxbuf + (t & 1) * 65536;
            const unsigned* p0 = (const unsigned*)(hx_r + ((long)(b0 + fr)) * 1024 + (k0 - 1024) + fq * 8);
            const unsigned* p1 = p0 + 8192;      // +16 rows * 1024 shorts = 8192 u32
#pragma unroll
            for (int s = 0; s < 4; ++s) {
                af[s]     = coh_load16B(p0 + s * 16);   // s*32 shorts = s*16 u32
                af[4 + s] = coh_load16B(p1 + s * 16);
            }
        }

        f32x4 acc[2][2] = {};
#pragma unroll
        for (int s = 0; s < 4; ++s)
#pragma unroll
            for (int mt = 0; mt < 2; ++mt)
#pragma unroll
                for (int nt = 0; nt < 2; ++nt)
                    acc[mt][nt] = __builtin_amdgcn_mfma_f32_16x16x32_bf16(
                        af[mt * 4 + s], breg[nt][s], acc[mt][nt], 0, 0, 0);

#pragma unroll
        for (int mt = 0; mt < 2; ++mt)
#pragma unroll
            for (int nt = 0; nt < 2; ++nt) {
                const int col = nt * 16 + fr;
                const int prow = (fq * 4) ^ ((col & 3) << 2);
                *(f32x4*)&zpart[kq][mt][col][prow] = acc[mt][nt];
            }
        __syncthreads();                          // #1: zpart ready

        if (tid < 256) {
            const int emt = eb >> 4, erow = eb & 15;
            float z[4];
#pragma unroll
            for (int g = 0; g < 4; ++g) {
                const int col = g * 8 + ehl;
                const int pr = erow ^ ((col & 3) << 2);
                float s = be[g];
#pragma unroll
                for (int q = 0; q < 16; ++q) s += zpart[q][emt][col][pr];
                z[g] = s;
            }
            float fg = 1.f / (1.f + __expf(-z[0]));
            float ig = 1.f / (1.f + __expf(-z[1]));
            float gg = 2.f / (1.f + __expf(-2.f * z[2])) - 1.f;
            float og = 1.f / (1.f + __expf(-z[3]));
            creg = fg * creg + ig * gg;
            float hv = og * (2.f / (1.f + __expf(-2.f * creg)) - 1.f);
            const int b = b0 + eb, h = ho + ehl;
            outs[((long)(t * 64 + b)) * 1024 + h] = hv;

            // hx write-through: pack even/odd h pair into one u32 agent store
            unsigned hb = (unsigned)f2bf(hv);
            unsigned ob = (unsigned)__shfl_xor((int)hb, 1);
            if ((tid & 1) == 0) {
                unsigned pack = (hb & 0xFFFFu) | (ob << 16);
                unsigned* hx_w = (unsigned*)(hxbuf + ((t + 1) & 1) * 65536 + b * 1024 + h);
                __hip_atomic_store(hx_w, pack, __ATOMIC_RELAXED, __HIP_MEMORY_SCOPE_AGENT);
            }
            if (t == TSTEPS - 1) { hxf[b * 1024 + h] = hv; cxf[b * 1024 + h] = creg; }
            vm_drain();                           // hx stores at LLC before barrier
        }
        __syncthreads();                          // #2: all epilogue stores drained
        if (tid == 0)
            __hip_atomic_store(flags + bid, (unsigned)(t + 1), __ATOMIC_RELAXED,
                               __HIP_MEMORY_SCOPE_AGENT);
    }
}

extern "C" void kernel_launch(void* const* d_in, const int* in_sizes, int n_in,
                              void* d_out, int out_size, void* d_ws, size_t ws_size,
                              hipStream_t stream) {
    (void)in_sizes; (void)n_in; (void)out_size;
    const float* x  = (const float*)d_in[0];
    const float* W1 = (const float*)d_in[1];
    const float* b1 = (const float*)d_in[2];
    const float* W2 = (const float*)d_in[3];
    const float* b2 = (const float*)d_in[4];
    float* outs = (float*)d_out;
    float* hxf = outs + 16777216L;
    float* cxf = hxf + 65536;

    // ws layout (bytes)
    const size_t off_wefft = 0;          // 16,777,216  WeffT bf16 [4][1024][2048]
    const size_t off_xbf   = 16777216;   // 33,554,432  xbf bf16 (w2t aliased at head)
    const size_t off_w2t   = off_xbf;    //  8,388,608  consumed before xconv overwrites
    const size_t off_hx    = 50331648;   //    262,144  hx ping-pong [2][64][1024] bf16
    const size_t off_beff  = 50593792;   //     16,384
    const size_t off_flags = 50610176;   //      1,024  flags[256]
    const size_t off_spin  = 50611200;   //      1,024  spin[256]
    const size_t need      = 50612224;
    if (ws_size < need) { hq_marker<<<1, 1, 0, stream>>>((float*)d_out); return; }

    char* ws = (char*)d_ws;
    unsigned short* wefft = (unsigned short*)(ws + off_wefft);
    unsigned short* xbf   = (unsigned short*)(ws + off_xbf);
    unsigned short* w2t   = (unsigned short*)(ws + off_w2t);
    unsigned short* hxbuf = (unsigned short*)(ws + off_hx);
    float* beff = (float*)(ws + off_beff);
    unsigned* flags = (unsigned*)(ws + off_flags);
    unsigned* spin  = (unsigned*)(ws + off_spin);

    hipMemsetAsync(ws + off_flags, 0, 2048, stream);   // flags + spin = 0 (every replay)
    hq_transpose<<<dim3(16, 16, 4), 256, 0, stream>>>(W2, w2t);
    hq_beff<<<dim3(4, 4), 256, 0, stream>>>(w2t, b1, b2, beff);
    hq_weff<<<dim3(32, 16, 4), 256, 0, stream>>>(w2t, W1, wefft);
    hq_xconv<<<2048, 256, 0, stream>>>(x, xbf);

    const unsigned short* xbf_c = xbf;
    const unsigned short* wefft_c = wefft;
    const float* beff_c = beff;
    void* args[] = { (void*)&xbf_c, (void*)&wefft_c, (void*)&beff_c,
                     (void*)&outs, (void*)&hxf, (void*)&cxf,
                     (void*)&hxbuf, (void*)&flags, (void*)&spin };
    hipError_t ce = hipLaunchCooperativeKernel((const void*)hq_seq, dim3(NBLK), dim3(1024),
                                               args, 0, stream);
    if (ce != hipSuccess) {
        // 1 block/CU by resource limits; 256 blocks <= 256 CUs -> co-resident anyway
        hq_seq<<<NBLK, 1024, 0, stream>>>(xbf, wefft, beff, outs, hxf, cxf, hxbuf, flags, spin);
    }
}

// Round 6
// 2216.797 us; speedup vs baseline: 2.3782x; 1.5853x over previous
//
#include <hip/hip_runtime.h>
#include <hip/hip_bf16.h>

#define TSTEPS 256
#define NBLK 256

typedef short bf16x8 __attribute__((ext_vector_type(8)));
typedef float f32x4 __attribute__((ext_vector_type(4)));

__device__ __forceinline__ unsigned short f2bf(float f) {
    union { float f; unsigned u; } v; v.f = f;
    unsigned r = v.u + 0x7FFFu + ((v.u >> 16) & 1u);
    return (unsigned short)(r >> 16);
}
__device__ __forceinline__ float bf2f(unsigned short s) {
    union { unsigned u; float f; } v; v.u = ((unsigned)s) << 16; return v.f;
}

__global__ void hq_marker(float* out) { out[0] = 12345.0f; }

// W2 [4][1024 k][1024 h] f32  ->  W2T [4][1024 h][1024 k] bf16
__global__ void hq_transpose(const float* __restrict__ in, unsigned short* __restrict__ out) {
    __shared__ float tile[64][65];
    const int R = 1024, C = 1024;
    int r0 = blockIdx.y * 64, c0 = blockIdx.x * 64;
    const float* src = in + (long)blockIdx.z * R * C;
    unsigned short* dst = out + (long)blockIdx.z * R * C;
    int col = threadIdx.x & 63, rr = threadIdx.x >> 6;
#pragma unroll
    for (int i = 0; i < 16; ++i) {
        int row = rr + i * 4;
        tile[row][col] = src[(long)(r0 + row) * C + c0 + col];
    }
    __syncthreads();
#pragma unroll
    for (int i = 0; i < 16; ++i) {
        int row = rr + i * 4;
        dst[(long)(c0 + row) * R + r0 + col] = f2bf(tile[col][row]);
    }
}

// beff[g][h] = sum_k b1[g][k]*W2[g][k][h] + b2[g][h]
__global__ void hq_beff(const unsigned short* __restrict__ w2t, const float* __restrict__ b1,
                        const float* __restrict__ b2, float* __restrict__ beff) {
    int g = blockIdx.y;
    int h = blockIdx.x * 256 + threadIdx.x;
    const unsigned short* row = w2t + ((long)(g * 1024 + h)) * 1024;
    float s = 0.f;
    for (int k = 0; k < 1024; k += 8) {
        bf16x8 v = *reinterpret_cast<const bf16x8*>(row + k);
#pragma unroll
        for (int j = 0; j < 8; ++j) s += bf2f((unsigned short)v[j]) * b1[g * 1024 + k + j];
    }
    beff[g * 1024 + h] = s + b2[g * 1024 + h];
}

// WeffT[g][h][d] = sum_k W2T[g][h][k] * W1[g][d][k]
__global__ void hq_weff(const unsigned short* __restrict__ w2t, const float* __restrict__ w1,
                        unsigned short* __restrict__ wefft) {
    __shared__ unsigned short atile[64][136];
    const int g = blockIdx.z;
    const int d0 = blockIdx.x * 64;
    const int h0 = blockIdx.y * 64;
    const int tid = threadIdx.x;
    const int w = tid >> 6, lane = tid & 63;
    const int fr = lane & 15, fq = lane >> 4;
    f32x4 acc[4] = {};
    const int drow = d0 + w * 16 + fr;
    const float* bsrc = w1 + ((long)g * 2048 + drow) * 1024;
    for (int kc = 0; kc < 8; ++kc) {
#pragma unroll
        for (int i = 0; i < 4; ++i) {
            int id = tid + i * 256;
            int row = id >> 4, c8 = id & 15;
            bf16x8 v = *reinterpret_cast<const bf16x8*>(
                w2t + ((long)(g * 1024 + h0 + row)) * 1024 + kc * 128 + c8 * 8);
            *reinterpret_cast<bf16x8*>(&atile[row][c8 * 8]) = v;
        }
        __syncthreads();
#pragma unroll
        for (int kk = 0; kk < 4; ++kk) {
            int kl = kk * 32 + fq * 8;
            int kg = kc * 128 + kl;
            float4 bA = *reinterpret_cast<const float4*>(bsrc + kg);
            float4 bB = *reinterpret_cast<const float4*>(bsrc + kg + 4);
            bf16x8 bfv;
            bfv[0] = (short)f2bf(bA.x); bfv[1] = (short)f2bf(bA.y);
            bfv[2] = (short)f2bf(bA.z); bfv[3] = (short)f2bf(bA.w);
            bfv[4] = (short)f2bf(bB.x); bfv[5] = (short)f2bf(bB.y);
            bfv[6] = (short)f2bf(bB.z); bfv[7] = (short)f2bf(bB.w);
#pragma unroll
            for (int mi = 0; mi < 4; ++mi) {
                bf16x8 af = *reinterpret_cast<const bf16x8*>(&atile[mi * 16 + fr][kl]);
                acc[mi] = __builtin_amdgcn_mfma_f32_16x16x32_bf16(af, bfv, acc[mi], 0, 0, 0);
            }
        }
        __syncthreads();
    }
#pragma unroll
    for (int mi = 0; mi < 4; ++mi)
#pragma unroll
        for (int r = 0; r < 4; ++r) {
            int h = h0 + mi * 16 + fq * 4 + r;
            int d = d0 + w * 16 + fr;
            wefft[((long)(g * 1024 + h)) * 2048 + d] = f2bf(acc[mi][r]);
        }
}

// inputs f32 -> bf16
__global__ void hq_xconv(const float* __restrict__ x, unsigned short* __restrict__ xbf) {
    long i = (long)blockIdx.x * 256 + threadIdx.x;
    for (; i < 4194304L; i += 524288L) {
        float4 v = reinterpret_cast<const float4*>(x)[i];
        ushort4 o;
        o.x = f2bf(v.x); o.y = f2bf(v.y); o.z = f2bf(v.z); o.w = f2bf(v.w);
        reinterpret_cast<ushort4*>(xbf)[i] = o;
    }
}

// Wide coherent hx load: 8x dwordx4 from LLC (sc0 sc1 = bypass L1+L2), one wait.
__device__ __forceinline__ void coh_load_hx(const void* pa, const void* pb, bf16x8* af) {
    asm volatile(
        "global_load_dwordx4 %0, %[a], off sc0 sc1\n\t"
        "global_load_dwordx4 %1, %[a], off offset:64 sc0 sc1\n\t"
        "global_load_dwordx4 %2, %[a], off offset:128 sc0 sc1\n\t"
        "global_load_dwordx4 %3, %[a], off offset:192 sc0 sc1\n\t"
        "global_load_dwordx4 %4, %[b], off sc0 sc1\n\t"
        "global_load_dwordx4 %5, %[b], off offset:64 sc0 sc1\n\t"
        "global_load_dwordx4 %6, %[b], off offset:128 sc0 sc1\n\t"
        "global_load_dwordx4 %7, %[b], off offset:192 sc0 sc1\n\t"
        "s_waitcnt vmcnt(0)"
        : "=&v"(af[0]), "=&v"(af[1]), "=&v"(af[2]), "=&v"(af[3]),
          "=&v"(af[4]), "=&v"(af[5]), "=&v"(af[6]), "=&v"(af[7])
        : [a] "v"(pa), [b] "v"(pb)
        : "memory");
}
__device__ __forceinline__ void vm_drain() {
    asm volatile("s_waitcnt vmcnt(0)" ::: "memory");
}

// Persistent sequential kernel, fence-free flag barrier (bq-group rendezvous).
// grid 256 = (bq 2) x (cb 128); block 1024 = 16 waves, wave kq owns 128 K-slice.
// kq 0-7: x part (never waits). kq 8-15: hx part (wave 8 polls 128 same-bq flags,
// relays via LDS). waves 0-3: epilogue; outs stored after flag publish.
__global__ __launch_bounds__(1024, 4) void hq_seq(
    const unsigned short* __restrict__ xbf,     // [256][64][1024] bf16
    const unsigned short* __restrict__ wefft,   // [4][1024][2048] bf16
    const float* __restrict__ beff,             // [4][1024]
    float* __restrict__ outs,                   // [256][64][1024] f32
    float* __restrict__ hxf, float* __restrict__ cxf,
    unsigned short* __restrict__ hxbuf,         // [2][64][1024] bf16 (no init needed)
    unsigned* __restrict__ flags)               // [256] zeroed per launch
{
    __shared__ float zpart[16][2][32][16];      // 64 KB, row XOR-swizzled
    __shared__ unsigned ready;
    const int tid = threadIdx.x;
    const int lane = tid & 63, kq = tid >> 6;
    const int fr = lane & 15, fq = lane >> 4;
    const int bid = blockIdx.x;
    const int bq = bid >> 7, cb = bid & 127;
    const int b0 = bq * 32, ho = cb * 8;
    const int k0 = kq * 128;

    if (tid == 0) ready = 0;

    // ---- preload B fragments: [nt 2][ks 4] = 32 regs/lane ----
    bf16x8 breg[2][4];
#pragma unroll
    for (int nt = 0; nt < 2; ++nt) {
        const int col = nt * 16 + fr;
        const int g = col >> 3, hl = col & 7;
        const unsigned short* wrow = wefft + ((long)(g * 1024 + ho + hl)) * 2048 + k0 + fq * 8;
#pragma unroll
        for (int s = 0; s < 4; ++s) breg[nt][s] = *(const bf16x8*)(wrow + s * 32);
    }

    const int eb = tid >> 3, ehl = tid & 7;
    float creg = 0.f;
    float be[4] = {0.f, 0.f, 0.f, 0.f};
    if (tid < 256) {
#pragma unroll
        for (int g = 0; g < 4; ++g) be[g] = beff[g * 1024 + ho + ehl];
    }
    __syncthreads();                              // ready init visible

    for (int t = 0; t < TSTEPS; ++t) {
        bf16x8 af[8];                             // [mt*4 + s]
        if (kq < 8) {
            const unsigned short* p0 = xbf + ((long)(t * 64 + b0 + fr)) * 1024 + k0 + fq * 8;
            const unsigned short* p1 = p0 + 16 * 1024;
#pragma unroll
            for (int s = 0; s < 4; ++s) {
                af[s]     = *(const bf16x8*)(p0 + s * 32);
                af[4 + s] = *(const bf16x8*)(p1 + s * 32);
            }
        } else if (t == 0) {
#pragma unroll
            for (int i = 0; i < 8; ++i) af[i] = (bf16x8){0, 0, 0, 0, 0, 0, 0, 0};
        } else {
            if (kq == 8) {
                const unsigned* fp = flags + bq * 128 + lane * 2;
                for (int g = 0; g < (1 << 16); ++g) {
                    unsigned a = __hip_atomic_load(fp + 0, __ATOMIC_RELAXED,
                                                   __HIP_MEMORY_SCOPE_AGENT);
                    unsigned b = __hip_atomic_load(fp + 1, __ATOMIC_RELAXED,
                                                   __HIP_MEMORY_SCOPE_AGENT);
                    unsigned m = a < b ? a : b;
                    if (__all(m >= (unsigned)t)) break;
                }
                if (lane == 0)
                    __hip_atomic_store(&ready, (unsigned)t, __ATOMIC_RELAXED,
                                       __HIP_MEMORY_SCOPE_WORKGROUP);
            }
            int guard = 0;
            while (__hip_atomic_load(&ready, __ATOMIC_RELAXED,
                                     __HIP_MEMORY_SCOPE_WORKGROUP) < (unsigned)t) {
                __builtin_amdgcn_s_sleep(1);
                if (++guard > (1 << 20)) break;
            }
            const unsigned short* hx_r = hxbuf + (t & 1) * 65536;
            const char* pa = (const char*)(hx_r + ((long)(b0 + fr)) * 1024 + (k0 - 1024) + fq * 8);
            const char* pb = pa + 32768;          // +16 rows * 2048 B
            coh_load_hx(pa, pb, af);
        }

        f32x4 acc[2][2] = {};
#pragma unroll
        for (int s = 0; s < 4; ++s)
#pragma unroll
            for (int mt = 0; mt < 2; ++mt)
#pragma unroll
                for (int nt = 0; nt < 2; ++nt)
                    acc[mt][nt] = __builtin_amdgcn_mfma_f32_16x16x32_bf16(
                        af[mt * 4 + s], breg[nt][s], acc[mt][nt], 0, 0, 0);

#pragma unroll
        for (int mt = 0; mt < 2; ++mt)
#pragma unroll
            for (int nt = 0; nt < 2; ++nt) {
                const int col = nt * 16 + fr;
                const int prow = (fq * 4) ^ ((col & 3) << 2);
                *(f32x4*)&zpart[kq][mt][col][prow] = acc[mt][nt];
            }
        __syncthreads();                          // #1: zpart ready

        float hv_out = 0.f;
        if (tid < 256) {
            const int emt = eb >> 4, erow = eb & 15;
            float z[4];
#pragma unroll
            for (int g = 0; g < 4; ++g) {
                const int col = g * 8 + ehl;
                const int pr = erow ^ ((col & 3) << 2);
                float s = be[g];
#pragma unroll
                for (int q = 0; q < 16; ++q) s += zpart[q][emt][col][pr];
                z[g] = s;
            }
            float fg = 1.f / (1.f + __expf(-z[0]));
            float ig = 1.f / (1.f + __expf(-z[1]));
            float gg = 2.f / (1.f + __expf(-2.f * z[2])) - 1.f;
            float og = 1.f / (1.f + __expf(-z[3]));
            creg = fg * creg + ig * gg;
            hv_out = og * (2.f / (1.f + __expf(-2.f * creg)) - 1.f);
            const int b = b0 + eb, h = ho + ehl;

            // hx write-through: pack even/odd h pair into one u32 agent store
            unsigned hb = (unsigned)f2bf(hv_out);
            unsigned ob = (unsigned)__shfl_xor((int)hb, 1);
            if ((tid & 1) == 0) {
                unsigned pack = (hb & 0xFFFFu) | (ob << 16);
                unsigned* hx_w = (unsigned*)(hxbuf + ((t + 1) & 1) * 65536 + b * 1024 + h);
                __hip_atomic_store(hx_w, pack, __ATOMIC_RELAXED, __HIP_MEMORY_SCOPE_AGENT);
            }
            vm_drain();                           // hx stores at LLC before publish
        }
        __syncthreads();                          // #2: all hx stores drained
        if (tid == 0)
            __hip_atomic_store(flags + bid, (unsigned)(t + 1), __ATOMIC_RELAXED,
                               __HIP_MEMORY_SCOPE_AGENT);
        // off-critical-path stores (outs not consumed by other blocks)
        if (tid < 256) {
            const int b = b0 + eb, h = ho + ehl;
            outs[((long)(t * 64 + b)) * 1024 + h] = hv_out;
            if (t == TSTEPS - 1) { hxf[b * 1024 + h] = hv_out; cxf[b * 1024 + h] = creg; }
        }
    }
}

extern "C" void kernel_launch(void* const* d_in, const int* in_sizes, int n_in,
                              void* d_out, int out_size, void* d_ws, size_t ws_size,
                              hipStream_t stream) {
    (void)in_sizes; (void)n_in; (void)out_size;
    const float* x  = (const float*)d_in[0];
    const float* W1 = (const float*)d_in[1];
    const float* b1 = (const float*)d_in[2];
    const float* W2 = (const float*)d_in[3];
    const float* b2 = (const float*)d_in[4];
    float* outs = (float*)d_out;
    float* hxf = outs + 16777216L;
    float* cxf = hxf + 65536;

    // ws layout (bytes)
    const size_t off_wefft = 0;          // 16,777,216  WeffT bf16 [4][1024][2048]
    const size_t off_xbf   = 16777216;   // 33,554,432  xbf bf16 (w2t aliased at head)
    const size_t off_w2t   = off_xbf;    //  8,388,608  consumed before xconv overwrites
    const size_t off_hx    = 50331648;   //    262,144  hx ping-pong [2][64][1024] bf16
    const size_t off_beff  = 50593792;   //     16,384
    const size_t off_flags = 50610176;   //      1,024  flags[256]
    const size_t need      = 50611200;
    if (ws_size < need) { hq_marker<<<1, 1, 0, stream>>>((float*)d_out); return; }

    char* ws = (char*)d_ws;
    unsigned short* wefft = (unsigned short*)(ws + off_wefft);
    unsigned short* xbf   = (unsigned short*)(ws + off_xbf);
    unsigned short* w2t   = (unsigned short*)(ws + off_w2t);
    unsigned short* hxbuf = (unsigned short*)(ws + off_hx);
    float* beff = (float*)(ws + off_beff);
    unsigned* flags = (unsigned*)(ws + off_flags);

    hipMemsetAsync(ws + off_flags, 0, 1024, stream);   // flags = 0 (every replay)
    hq_transpose<<<dim3(16, 16, 4), 256, 0, stream>>>(W2, w2t);
    hq_beff<<<dim3(4, 4), 256, 0, stream>>>(w2t, b1, b2, beff);
    hq_weff<<<dim3(32, 16, 4), 256, 0, stream>>>(w2t, W1, wefft);
    hq_xconv<<<2048, 256, 0, stream>>>(x, xbf);

    const unsigned short* xbf_c = xbf;
    const unsigned short* wefft_c = wefft;
    const float* beff_c = beff;
    void* args[] = { (void*)&xbf_c, (void*)&wefft_c, (void*)&beff_c,
                     (void*)&outs, (void*)&hxf, (void*)&cxf,
                     (void*)&hxbuf, (void*)&flags };
    hipError_t ce = hipLaunchCooperativeKernel((const void*)hq_seq, dim3(NBLK), dim3(1024),
                                               args, 0, stream);
    if (ce != hipSuccess) {
        // 1 block/CU by resource limits; 256 blocks <= 256 CUs -> co-resident anyway
        hq_seq<<<NBLK, 1024, 0, stream>>>(xbf, wefft, beff, outs, hxf, cxf, hxbuf, flags);
    }
}

// Round 7
// 2165.168 us; speedup vs baseline: 2.4349x; 1.0238x over previous
//
#include <hip/hip_runtime.h>
#include <hip/hip_bf16.h>

#define TSTEPS 256
#define NBLK 256

typedef short bf16x8 __attribute__((ext_vector_type(8)));
typedef float f32x4 __attribute__((ext_vector_type(4)));
typedef unsigned u32x2 __attribute__((ext_vector_type(2)));

__device__ __forceinline__ unsigned short f2bf(float f) {
    union { float f; unsigned u; } v; v.f = f;
    unsigned r = v.u + 0x7FFFu + ((v.u >> 16) & 1u);
    return (unsigned short)(r >> 16);
}
__device__ __forceinline__ float bf2f(unsigned short s) {
    union { unsigned u; float f; } v; v.u = ((unsigned)s) << 16; return v.f;
}

__global__ void hq_marker(float* out) { out[0] = 12345.0f; }

// W2 [4][1024 k][1024 h] f32  ->  W2T [4][1024 h][1024 k] bf16
__global__ void hq_transpose(const float* __restrict__ in, unsigned short* __restrict__ out) {
    __shared__ float tile[64][65];
    const int R = 1024, C = 1024;
    int r0 = blockIdx.y * 64, c0 = blockIdx.x * 64;
    const float* src = in + (long)blockIdx.z * R * C;
    unsigned short* dst = out + (long)blockIdx.z * R * C;
    int col = threadIdx.x & 63, rr = threadIdx.x >> 6;
#pragma unroll
    for (int i = 0; i < 16; ++i) {
        int row = rr + i * 4;
        tile[row][col] = src[(long)(r0 + row) * C + c0 + col];
    }
    __syncthreads();
#pragma unroll
    for (int i = 0; i < 16; ++i) {
        int row = rr + i * 4;
        dst[(long)(c0 + row) * R + r0 + col] = f2bf(tile[col][row]);
    }
}

// beff[g][h] = sum_k b1[g][k]*W2[g][k][h] + b2[g][h]
__global__ void hq_beff(const unsigned short* __restrict__ w2t, const float* __restrict__ b1,
                        const float* __restrict__ b2, float* __restrict__ beff) {
    int g = blockIdx.y;
    int h = blockIdx.x * 256 + threadIdx.x;
    const unsigned short* row = w2t + ((long)(g * 1024 + h)) * 1024;
    float s = 0.f;
    for (int k = 0; k < 1024; k += 8) {
        bf16x8 v = *reinterpret_cast<const bf16x8*>(row + k);
#pragma unroll
        for (int j = 0; j < 8; ++j) s += bf2f((unsigned short)v[j]) * b1[g * 1024 + k + j];
    }
    beff[g * 1024 + h] = s + b2[g * 1024 + h];
}

// WeffT[g][h][d] = sum_k W2T[g][h][k] * W1[g][d][k]
__global__ void hq_weff(const unsigned short* __restrict__ w2t, const float* __restrict__ w1,
                        unsigned short* __restrict__ wefft) {
    __shared__ unsigned short atile[64][136];
    const int g = blockIdx.z;
    const int d0 = blockIdx.x * 64;
    const int h0 = blockIdx.y * 64;
    const int tid = threadIdx.x;
    const int w = tid >> 6, lane = tid & 63;
    const int fr = lane & 15, fq = lane >> 4;
    f32x4 acc[4] = {};
    const int drow = d0 + w * 16 + fr;
    const float* bsrc = w1 + ((long)g * 2048 + drow) * 1024;
    for (int kc = 0; kc < 8; ++kc) {
#pragma unroll
        for (int i = 0; i < 4; ++i) {
            int id = tid + i * 256;
            int row = id >> 4, c8 = id & 15;
            bf16x8 v = *reinterpret_cast<const bf16x8*>(
                w2t + ((long)(g * 1024 + h0 + row)) * 1024 + kc * 128 + c8 * 8);
            *reinterpret_cast<bf16x8*>(&atile[row][c8 * 8]) = v;
        }
        __syncthreads();
#pragma unroll
        for (int kk = 0; kk < 4; ++kk) {
            int kl = kk * 32 + fq * 8;
            int kg = kc * 128 + kl;
            float4 bA = *reinterpret_cast<const float4*>(bsrc + kg);
            float4 bB = *reinterpret_cast<const float4*>(bsrc + kg + 4);
            bf16x8 bfv;
            bfv[0] = (short)f2bf(bA.x); bfv[1] = (short)f2bf(bA.y);
            bfv[2] = (short)f2bf(bA.z); bfv[3] = (short)f2bf(bA.w);
            bfv[4] = (short)f2bf(bB.x); bfv[5] = (short)f2bf(bB.y);
            bfv[6] = (short)f2bf(bB.z); bfv[7] = (short)f2bf(bB.w);
#pragma unroll
            for (int mi = 0; mi < 4; ++mi) {
                bf16x8 af = *reinterpret_cast<const bf16x8*>(&atile[mi * 16 + fr][kl]);
                acc[mi] = __builtin_amdgcn_mfma_f32_16x16x32_bf16(af, bfv, acc[mi], 0, 0, 0);
            }
        }
        __syncthreads();
    }
#pragma unroll
    for (int mi = 0; mi < 4; ++mi)
#pragma unroll
        for (int r = 0; r < 4; ++r) {
            int h = h0 + mi * 16 + fq * 4 + r;
            int d = d0 + w * 16 + fr;
            wefft[((long)(g * 1024 + h)) * 2048 + d] = f2bf(acc[mi][r]);
        }
}

// inputs f32 -> bf16
__global__ void hq_xconv(const float* __restrict__ x, unsigned short* __restrict__ xbf) {
    long i = (long)blockIdx.x * 256 + threadIdx.x;
    for (; i < 4194304L; i += 524288L) {
        float4 v = reinterpret_cast<const float4*>(x)[i];
        ushort4 o;
        o.x = f2bf(v.x); o.y = f2bf(v.y); o.z = f2bf(v.z); o.w = f2bf(v.w);
        reinterpret_cast<ushort4*>(xbf)[i] = o;
    }
}

// Wide coherent hx load: 8x dwordx4 from LLC (sc0 sc1 = bypass L1+L2), one wait.
__device__ __forceinline__ void coh_load_hx(const void* pa, const void* pb, bf16x8* af) {
    asm volatile(
        "global_load_dwordx4 %0, %[a], off sc0 sc1\n\t"
        "global_load_dwordx4 %1, %[a], off offset:64 sc0 sc1\n\t"
        "global_load_dwordx4 %2, %[a], off offset:128 sc0 sc1\n\t"
        "global_load_dwordx4 %3, %[a], off offset:192 sc0 sc1\n\t"
        "global_load_dwordx4 %4, %[b], off sc0 sc1\n\t"
        "global_load_dwordx4 %5, %[b], off offset:64 sc0 sc1\n\t"
        "global_load_dwordx4 %6, %[b], off offset:128 sc0 sc1\n\t"
        "global_load_dwordx4 %7, %[b], off offset:192 sc0 sc1\n\t"
        "s_waitcnt vmcnt(0)"
        : "=&v"(af[0]), "=&v"(af[1]), "=&v"(af[2]), "=&v"(af[3]),
          "=&v"(af[4]), "=&v"(af[5]), "=&v"(af[6]), "=&v"(af[7])
        : [a] "v"(pa), [b] "v"(pb)
        : "memory");
}
// Coherent 8B flag read (one instruction for 2 flags/lane)
__device__ __forceinline__ u32x2 coh_load_flags(const unsigned* p) {
    u32x2 r;
    asm volatile(
        "global_load_dwordx2 %0, %[a], off sc0 sc1\n\t"
        "s_waitcnt vmcnt(0)"
        : "=&v"(r) : [a] "v"(p) : "memory");
    return r;
}
__device__ __forceinline__ void vm_drain() {
    asm volatile("s_waitcnt vmcnt(0)" ::: "memory");
}

// Persistent sequential kernel, fence-free flag barrier (bq-group rendezvous).
// grid 256 = (bq 2) x (cb 128); block 1024 = 16 waves, wave kq owns 128 K-slice.
// Wave roles: kq0-7 x-load+MFMA; kq0-3 also epilogue (gates + hx LLC store + publish,
// NO HBM traffic). kq8 polls 128 same-bq flags, relays via LDS. kq8-15 hx-load+MFMA.
// kq12-15 do the outs/hxf/cxf HBM stores via LDS handoff (ack lands in their
// next-step ready-spin slack, off the critical publish chain).
__global__ __launch_bounds__(1024, 4) void hq_seq(
    const unsigned short* __restrict__ xbf,     // [256][64][1024] bf16
    const unsigned short* __restrict__ wefft,   // [4][1024][2048] bf16
    const float* __restrict__ beff,             // [4][1024]
    float* __restrict__ outs,                   // [256][64][1024] f32
    float* __restrict__ hxf, float* __restrict__ cxf,
    unsigned short* __restrict__ hxbuf,         // [2][64][1024] bf16 (no init needed)
    unsigned* __restrict__ flags)               // [256] zeroed per launch
{
    __shared__ float zpart[16][2][32][16];      // 64 KB, row XOR-swizzled
    __shared__ float hvbuf[256];                // hv handoff epilogue -> waves 12-15
    __shared__ float cbuf[256];                 // creg handoff (final step only)
    __shared__ unsigned ready;
    const int tid = threadIdx.x;
    const int lane = tid & 63, kq = tid >> 6;
    const int fr = lane & 15, fq = lane >> 4;
    const int bid = blockIdx.x;
    const int bq = bid >> 7, cb = bid & 127;
    const int b0 = bq * 32, ho = cb * 8;
    const int k0 = kq * 128;

    if (tid == 0) ready = 0;

    // ---- preload B fragments: [nt 2][ks 4] = 32 regs/lane ----
    bf16x8 breg[2][4];
#pragma unroll
    for (int nt = 0; nt < 2; ++nt) {
        const int col = nt * 16 + fr;
        const int g = col >> 3, hl = col & 7;
        const unsigned short* wrow = wefft + ((long)(g * 1024 + ho + hl)) * 2048 + k0 + fq * 8;
#pragma unroll
        for (int s = 0; s < 4; ++s) breg[nt][s] = *(const bf16x8*)(wrow + s * 32);
    }

    const int eb = tid >> 3, ehl = tid & 7;
    float creg = 0.f;
    float be[4] = {0.f, 0.f, 0.f, 0.f};
    if (tid < 256) {
#pragma unroll
        for (int g = 0; g < 4; ++g) be[g] = beff[g * 1024 + ho + ehl];
    }
    __syncthreads();                              // ready init visible

    for (int t = 0; t < TSTEPS; ++t) {
        bf16x8 af[8];                             // [mt*4 + s]
        if (kq < 8) {
            const unsigned short* p0 = xbf + ((long)(t * 64 + b0 + fr)) * 1024 + k0 + fq * 8;
            const unsigned short* p1 = p0 + 16 * 1024;
#pragma unroll
            for (int s = 0; s < 4; ++s) {
                af[s]     = *(const bf16x8*)(p0 + s * 32);
                af[4 + s] = *(const bf16x8*)(p1 + s * 32);
            }
        } else if (t == 0) {
#pragma unroll
            for (int i = 0; i < 8; ++i) af[i] = (bf16x8){0, 0, 0, 0, 0, 0, 0, 0};
        } else {
            if (kq == 8) {
                const unsigned* fp = flags + bq * 128 + lane * 2;
                for (int g = 0; g < (1 << 16); ++g) {
                    u32x2 v = coh_load_flags(fp);
                    unsigned m = v.x < v.y ? v.x : v.y;
                    if (__all(m >= (unsigned)t)) break;
                }
                if (lane == 0)
                    __hip_atomic_store(&ready, (unsigned)t, __ATOMIC_RELAXED,
                                       __HIP_MEMORY_SCOPE_WORKGROUP);
            }
            int guard = 0;
            while (__hip_atomic_load(&ready, __ATOMIC_RELAXED,
                                     __HIP_MEMORY_SCOPE_WORKGROUP) < (unsigned)t) {
                __builtin_amdgcn_s_sleep(1);
                if (++guard > (1 << 20)) break;
            }
            const unsigned short* hx_r = hxbuf + (t & 1) * 65536;
            const char* pa = (const char*)(hx_r + ((long)(b0 + fr)) * 1024 + (k0 - 1024) + fq * 8);
            const char* pb = pa + 32768;          // +16 rows * 2048 B
            coh_load_hx(pa, pb, af);
        }

        f32x4 acc[2][2] = {};
#pragma unroll
        for (int s = 0; s < 4; ++s)
#pragma unroll
            for (int mt = 0; mt < 2; ++mt)
#pragma unroll
                for (int nt = 0; nt < 2; ++nt)
                    acc[mt][nt] = __builtin_amdgcn_mfma_f32_16x16x32_bf16(
                        af[mt * 4 + s], breg[nt][s], acc[mt][nt], 0, 0, 0);

#pragma unroll
        for (int mt = 0; mt < 2; ++mt)
#pragma unroll
            for (int nt = 0; nt < 2; ++nt) {
                const int col = nt * 16 + fr;
                const int prow = (fq * 4) ^ ((col & 3) << 2);
                *(f32x4*)&zpart[kq][mt][col][prow] = acc[mt][nt];
            }
        __syncthreads();                          // #1: zpart ready

        if (tid < 256) {
            const int emt = eb >> 4, erow = eb & 15;
            float z[4];
#pragma unroll
            for (int g = 0; g < 4; ++g) {
                const int col = g * 8 + ehl;
                const int pr = erow ^ ((col & 3) << 2);
                float s = be[g];
#pragma unroll
                for (int q = 0; q < 16; ++q) s += zpart[q][emt][col][pr];
                z[g] = s;
            }
            float fg = 1.f / (1.f + __expf(-z[0]));
            float ig = 1.f / (1.f + __expf(-z[1]));
            float gg = 2.f / (1.f + __expf(-2.f * z[2])) - 1.f;
            float og = 1.f / (1.f + __expf(-z[3]));
            creg = fg * creg + ig * gg;
            float hv = og * (2.f / (1.f + __expf(-2.f * creg)) - 1.f);
            const int b = b0 + eb, h = ho + ehl;
            hvbuf[tid] = hv;
            if (t == TSTEPS - 1) cbuf[tid] = creg;

            // hx write-through: pack even/odd h pair into one u32 agent store
            unsigned hb = (unsigned)f2bf(hv);
            unsigned ob = (unsigned)__shfl_xor((int)hb, 1);
            if ((tid & 1) == 0) {
                unsigned pack = (hb & 0xFFFFu) | (ob << 16);
                unsigned* hx_w = (unsigned*)(hxbuf + ((t + 1) & 1) * 65536 + b * 1024 + h);
                __hip_atomic_store(hx_w, pack, __ATOMIC_RELAXED, __HIP_MEMORY_SCOPE_AGENT);
            }
            vm_drain();                           // waits ONLY the hx LLC stores now
        }
        __syncthreads();                          // #2: hx drained + hvbuf visible
        if (tid == 0)
            __hip_atomic_store(flags + bid, (unsigned)(t + 1), __ATOMIC_RELAXED,
                               __HIP_MEMORY_SCOPE_AGENT);
        // HBM stores by waves 12-15 (ack absorbed by next-step ready-spin slack)
        if (tid >= 768) {
            const int et = tid - 768;
            const int b = b0 + (et >> 3), h = ho + (et & 7);
            float hv = hvbuf[et];
            outs[((long)(t * 64 + b)) * 1024 + h] = hv;
            if (t == TSTEPS - 1) { hxf[b * 1024 + h] = hv; cxf[b * 1024 + h] = cbuf[et]; }
        }
    }
}

extern "C" void kernel_launch(void* const* d_in, const int* in_sizes, int n_in,
                              void* d_out, int out_size, void* d_ws, size_t ws_size,
                              hipStream_t stream) {
    (void)in_sizes; (void)n_in; (void)out_size;
    const float* x  = (const float*)d_in[0];
    const float* W1 = (const float*)d_in[1];
    const float* b1 = (const float*)d_in[2];
    const float* W2 = (const float*)d_in[3];
    const float* b2 = (const float*)d_in[4];
    float* outs = (float*)d_out;
    float* hxf = outs + 16777216L;
    float* cxf = hxf + 65536;

    // ws layout (bytes)
    const size_t off_wefft = 0;          // 16,777,216  WeffT bf16 [4][1024][2048]
    const size_t off_xbf   = 16777216;   // 33,554,432  xbf bf16 (w2t aliased at head)
    const size_t off_w2t   = off_xbf;    //  8,388,608  consumed before xconv overwrites
    const size_t off_hx    = 50331648;   //    262,144  hx ping-pong [2][64][1024] bf16
    const size_t off_beff  = 50593792;   //     16,384
    const size_t off_flags = 50610176;   //      1,024  flags[256]
    const size_t need      = 50611200;
    if (ws_size < need) { hq_marker<<<1, 1, 0, stream>>>((float*)d_out); return; }

    char* ws = (char*)d_ws;
    unsigned short* wefft = (unsigned short*)(ws + off_wefft);
    unsigned short* xbf   = (unsigned short*)(ws + off_xbf);
    unsigned short* w2t   = (unsigned short*)(ws + off_w2t);
    unsigned short* hxbuf = (unsigned short*)(ws + off_hx);
    float* beff = (float*)(ws + off_beff);
    unsigned* flags = (unsigned*)(ws + off_flags);

    hipMemsetAsync(ws + off_flags, 0, 1024, stream);   // flags = 0 (every replay)
    hq_transpose<<<dim3(16, 16, 4), 256, 0, stream>>>(W2, w2t);
    hq_beff<<<dim3(4, 4), 256, 0, stream>>>(w2t, b1, b2, beff);
    hq_weff<<<dim3(32, 16, 4), 256, 0, stream>>>(w2t, W1, wefft);
    hq_xconv<<<2048, 256, 0, stream>>>(x, xbf);

    const unsigned short* xbf_c = xbf;
    const unsigned short* wefft_c = wefft;
    const float* beff_c = beff;
    void* args[] = { (void*)&xbf_c, (void*)&wefft_c, (void*)&beff_c,
                     (void*)&outs, (void*)&hxf, (void*)&cxf,
                     (void*)&hxbuf, (void*)&flags };
    hipError_t ce = hipLaunchCooperativeKernel((const void*)hq_seq, dim3(NBLK), dim3(1024),
                                               args, 0, stream);
    if (ce != hipSuccess) {
        // 1 block/CU by resource limits; 256 blocks <= 256 CUs -> co-resident anyway
        hq_seq<<<NBLK, 1024, 0, stream>>>(xbf, wefft, beff, outs, hxf, cxf, hxbuf, flags);
    }
}